// Round 15
// baseline (18.055 us; speedup 1.0000x reference)
//
#include <hip/hip_runtime.h>

// Warp_Object bicubic warp: B=4, C=3, H=512, W=512, float32.
// Round 15: 4-deep rolling pipeline. Block = vertical strip of 4 32x32
// tiles, double-buffered LDS (2 x 25,344B). Per iter (guide T3 minimum-
// 2-phase): dx/dy(t+1) + stage(t+1)->buf^1 issued BEFORE stencil(t) from
// buf; coef(t+1) after stores (overlaps staging flight); ONE vmcnt(3)
// (3 NT stores stay in flight; stage(t+1) guaranteed landed) + raw
// s_barrier per iter. Steady-state: staging streams under stencil, CUs
// desynchronize. Grid = 256 blocks = 1/CU, 16 waves/CU.

constexpr int B = 4, C = 3, H = 512, W = 512;
constexpr int HW = H * W;              // 2^18
constexpr int TS = 32;                 // tile size
constexpr int NTILE = 4;               // tiles per block (vertical strip)
constexpr int HALO = 6;
constexpr int RS = TS + 2 * HALO;      // 44 staged rows
constexpr int LSTC = 48;               // staged cols; %32=16 bank rotate
constexpr int CHR = LSTC / 4;          // 12 f4 chunks per staged row
constexpr int NCH = RS * CHR;          // 528 chunks per plane
constexpr int CPW = NCH / 16;          // 33 chunks per wave per plane
constexpr int TDW = RS * LSTC;         // 2112 dwords per plane
constexpr int NT = 1024;
constexpr int NB = 256;                // 1 block per CU

typedef float f4 __attribute__((ext_vector_type(4)));
typedef f4 f4u __attribute__((aligned(4)));   // 4B-aligned float4 load

typedef const __attribute__((address_space(1))) void* gas_t;
typedef __attribute__((address_space(3))) void* las_t;

__device__ __forceinline__ void gload_lds16(const float* g, float* l) {
    __builtin_amdgcn_global_load_lds((gas_t)g, (las_t)l, 16, 0, 0);
}

struct Coef {
    float w0, w1, w2, w3;     // x-weights (image-edge clamp folded)
    float cy0, cy1, cy2, cy3; // y-coefficients
    int   lbase;              // LDS dword base
    bool  intile;
    int   y0, s;              // for the rare global fallback
};

__device__ __forceinline__ Coef make_coef(int x, int y, float dxv, float dyv,
                                          int yb, int cb) {
    Coef cf;
    float xm = (float)x + dxv;             // == ref up to ~3e-5 px rounding
    float ym = (float)y + dyv;
    float x0f = floorf(xm), y0f = floorf(ym);
    float ftx = xm - x0f, fty = ym - y0f;
    int x0 = (int)x0f, y0 = (int)y0f;
    int s  = min(max(x0 - 1, 0), W - 4);

    float tx2 = ftx * ftx, tx3 = tx2 * ftx;
    float cx0 = (-tx3 + 2.0f * tx2 - ftx) * 0.5f;
    float cx1 = (3.0f * tx3 - 5.0f * tx2 + 2.0f) * 0.5f;
    float cx2 = (-3.0f * tx3 + 4.0f * tx2 + ftx) * 0.5f;
    float cx3 = 1.0f - (cx0 + cx1 + cx2);

    float ty2 = fty * fty, ty3 = ty2 * fty;
    cf.cy0 = (-ty3 + 2.0f * ty2 - fty) * 0.5f;
    cf.cy1 = (3.0f * ty3 - 5.0f * ty2 + 2.0f) * 0.5f;
    cf.cy2 = (-3.0f * ty3 + 4.0f * ty2 + fty) * 0.5f;
    cf.cy3 = 1.0f - (cf.cy0 + cf.cy1 + cf.cy2);

    if (__builtin_expect(x0 >= 1 && x0 <= W - 3, 1)) {
        cf.w0 = cx0; cf.w1 = cx1; cf.w2 = cx2; cf.w3 = cx3;
    } else {                               // fold image-edge taps into window
        float w0 = 0.f, w1 = 0.f, w2 = 0.f, w3 = 0.f;
        const float cxa[4] = {cx0, cx1, cx2, cx3};
#pragma unroll
        for (int o = 0; o < 4; ++o) {
            int xi = min(max(x0 - 1 + o, 0), W - 1);
            int e  = xi - s;               // 0..3 always
            float cc = cxa[o];
            w0 += (e == 0) ? cc : 0.f;
            w1 += (e == 1) ? cc : 0.f;
            w2 += (e == 2) ? cc : 0.f;
            w3 += (e == 3) ? cc : 0.f;
        }
        cf.w0 = w0; cf.w1 = w1; cf.w2 = w2; cf.w3 = w3;
    }

    unsigned rel = (unsigned)(y0 - (yb - HALO + 1));
    unsigned lsv = (unsigned)(s - cb);
    cf.intile = (rel <= (unsigned)(RS - 4)) & (lsv <= (unsigned)(LSTC - 4));
    cf.lbase  = (int)rel * LSTC + (int)lsv;
    cf.y0 = y0; cf.s = s;
    return cf;
}

__device__ __forceinline__ float stencil1(const float* __restrict__ tp,
                                          const Coef& cf,
                                          const float* __restrict__ plane) {
    if (__builtin_expect(cf.intile, 1)) {
        const float* rp = tp + cf.lbase;
        float r0 = cf.cy0 * (cf.w0 * rp[0] + cf.w1 * rp[1] + cf.w2 * rp[2] + cf.w3 * rp[3]);
        rp += LSTC;
        float r1 = cf.cy1 * (cf.w0 * rp[0] + cf.w1 * rp[1] + cf.w2 * rp[2] + cf.w3 * rp[3]);
        rp += LSTC;
        float r2 = cf.cy2 * (cf.w0 * rp[0] + cf.w1 * rp[1] + cf.w2 * rp[2] + cf.w3 * rp[3]);
        rp += LSTC;
        float r3 = cf.cy3 * (cf.w0 * rp[0] + cf.w1 * rp[1] + cf.w2 * rp[2] + cf.w3 * rp[3]);
        return (r0 + r1) + (r2 + r3);
    } else {
        // rare Gaussian-tail escape: always-correct global path (drains vmcnt
        // for this wave only; P(wave hits it) ~ a few %, perf noise)
        const float cya[4] = {cf.cy0, cf.cy1, cf.cy2, cf.cy3};
        float acc = 0.f;
#pragma unroll
        for (int j = 0; j < 4; ++j) {
            int yi = min(max(cf.y0 - 1 + j, 0), H - 1);
            f4 v = *(const f4u*)(plane + yi * W + cf.s);
            acc += cya[j] * (cf.w0 * v.x + cf.w1 * v.y + cf.w2 * v.z + cf.w3 * v.w);
        }
        return acc;
    }
}

__device__ __forceinline__ void stage_tile(const float* __restrict__ img, int bd,
                                           int yb, int cb, float* dst,
                                           int wv, int lane) {
    if (lane < CPW) {                      // 33 active lanes; 3 instr per wave
        int chunk = wv * CPW + lane;       // < 528
        int r  = chunk / CHR;
        int c4 = (chunk - r * CHR) * 4;
        int sr = min(max(yb - HALO + r, 0), H - 1);   // y clamp == ref clamp
        int soff = sr * W + cb + c4;                  // always in-bounds
        const float* g0 = img + (size_t)bd * HW + soff;
        float* l0 = dst + chunk * 4;
        gload_lds16(g0,          l0);
        gload_lds16(g0 + 4 * HW, l0 + TDW);
        gload_lds16(g0 + 8 * HW, l0 + 2 * TDW);
    }
}

__global__ __launch_bounds__(NT, 4)
void warp_bicubic_strip(const float* __restrict__ img,
                        const float* __restrict__ dxp,
                        const float* __restrict__ dyp,
                        float* __restrict__ out)
{
    __shared__ float tile[2][C * TDW];         // 50,688 B

    int b   = blockIdx.x;
    int swz = (b & 7) * (NB / 8) + (b >> 3);   // XCD-chunked, bijective (256=8*32)
    int bd   = swz >> 6;                       // displacement batch 0..3
    int rem  = swz & 63;
    int sc   = rem & 15;                       // strip col 0..15
    int srow = rem >> 4;                       // strip row 0..3
    int xb   = sc * TS;
    int cb   = min(max(xb - HALO, 0), W - LSTC);
    int yb0  = srow * (NTILE * TS);            // 0,128,256,384

    int tid  = threadIdx.x;
    int wv   = tid >> 6;                       // 0..15
    int lane = tid & 63;
    int ry   = wv * 2 + (lane >> 5);           // 0..31
    int x    = xb + (lane & 31);

    // ---- prologue: dx/dy(t0) first, stage(t0), coef(t0) under flight ----
    {
        int po = (yb0 + ry) * W + x;
        float dxv = __builtin_nontemporal_load(dxp + bd * HW + po);
        float dyv = __builtin_nontemporal_load(dyp + bd * HW + po);
        // consume below in make_coef: auto-wait leaves stage outstanding
        stage_tile(img, bd, yb0, cb, &tile[0][0], wv, lane);
        Coef cf = make_coef(x, yb0 + ry, dxv, dyv, yb0, cb);

        asm volatile("s_waitcnt vmcnt(0)" ::: "memory");
        __builtin_amdgcn_sched_barrier(0);
        __builtin_amdgcn_s_barrier();
        __builtin_amdgcn_sched_barrier(0);

        // ---- rolling 4-tile pipeline ----
#pragma unroll
        for (int t = 0; t < NTILE; ++t) {
            int yb  = yb0 + t * TS;
            int poT = (yb + ry) * W + x;

            float dxn = 0.f, dyn = 0.f;
            if (t + 1 < NTILE) {               // issue next tile's inputs first
                int poN = (yb + TS + ry) * W + x;
                dxn = __builtin_nontemporal_load(dxp + bd * HW + poN);
                dyn = __builtin_nontemporal_load(dyp + bd * HW + poN);
                stage_tile(img, bd, yb + TS, cb, &tile[(t + 1) & 1][0], wv, lane);
            }
            __builtin_amdgcn_sched_barrier(0);

            // stencil current tile from buf[t&1] + NT stores
#pragma unroll
            for (int c = 0; c < C; ++c) {
                int kp = bd + 4 * c;
                float acc = stencil1(&tile[t & 1][c * TDW], cf,
                                     img + (size_t)kp * HW);
                __builtin_nontemporal_store(acc, out + (size_t)kp * HW + poT);
            }
            __builtin_amdgcn_sched_barrier(0);

            if (t + 1 < NTILE) {
                // next coef overlaps stage flight (auto-wait drains only dx/dy)
                Coef cfN = make_coef(x, yb + TS + ry, dxn, dyn, yb + TS, cb);
                // gate: stage(t+1) landed; the 3 NT stores stay in flight
                asm volatile("s_waitcnt vmcnt(3)" ::: "memory");
                __builtin_amdgcn_sched_barrier(0);
                __builtin_amdgcn_s_barrier();
                __builtin_amdgcn_sched_barrier(0);
                cf = cfN;
            }
        }
    }
}

extern "C" void kernel_launch(void* const* d_in, const int* in_sizes, int n_in,
                              void* d_out, int out_size, void* d_ws, size_t ws_size,
                              hipStream_t stream) {
    const float* img = (const float*)d_in[0];
    const float* dx  = (const float*)d_in[1];
    const float* dy  = (const float*)d_in[2];
    float* out = (float*)d_out;

    dim3 block(NT);
    dim3 grid(NB);   // 256 blocks = 1 per CU, 4 tiles each
    hipLaunchKernelGGL(warp_bicubic_strip, grid, block, 0, stream,
                       img, dx, dy, out);
}

// Round 16
// 16.547 us; speedup vs baseline: 1.0911x; 1.0911x over previous
//
#include <hip/hip_runtime.h>

// Warp_Object bicubic warp: B=4, C=3, H=512, W=512, float32.
// Round 16: r13 structure (best: 16.05us), taller tile. 64x32 output tile:
// halo amp 2.06->1.78, half the blocks (512) -> half the cold staging
// drains, staging = exactly 1 gload_lds per wave per plane (57 lanes).
// Single barrier, all 3 planes staged at once (76x48x3 = 43.8KB), coeffs
// computed once per px and reused x3 planes (displacement-share quirk).
// 2 blocks/CU = 32 waves/CU. Gaussian-tail escapees -> global fallback.

constexpr int B = 4, C = 3, H = 512, W = 512;
constexpr int HW = H * W;              // 2^18
constexpr int TSY = 64, TSX = 32;      // output tile
constexpr int HALO = 6;
constexpr int RS = TSY + 2 * HALO;     // 76 staged rows
constexpr int LSTC = 48;               // staged cols; %32=16 bank rotate
constexpr int CHR = LSTC / 4;          // 12 f4 chunks per staged row
constexpr int NCH = RS * CHR;          // 912 chunks per plane
constexpr int CPW = NCH / 16;          // 57 chunks per wave per plane
constexpr int TDW = RS * LSTC;         // 3648 dwords per plane
constexpr int NPOS = 2;
constexpr int NT = 1024;
constexpr int NB = B * (H / TSY) * (W / TSX);   // 512 blocks

typedef float f4 __attribute__((ext_vector_type(4)));
typedef f4 f4u __attribute__((aligned(4)));   // 4B-aligned float4 load

typedef const __attribute__((address_space(1))) void* gas_t;
typedef __attribute__((address_space(3))) void* las_t;

__device__ __forceinline__ void gload_lds16(const float* g, float* l) {
    __builtin_amdgcn_global_load_lds((gas_t)g, (las_t)l, 16, 0, 0);
}

__global__ __launch_bounds__(NT, 8)
void warp_bicubic_tall(const float* __restrict__ img,
                       const float* __restrict__ dxp,
                       const float* __restrict__ dyp,
                       float* __restrict__ out)
{
    __shared__ float tile[C][TDW];             // 43,776 B -> 2 blocks/CU

    int b   = blockIdx.x;
    int swz = (b & 7) * (NB / 8) + (b >> 3);   // XCD-chunked, bijective (512=8*64)
    int bd  = swz >> 7;                        // displacement batch 0..3
    int rem = swz & 127;
    int ysr = rem >> 4;                        // y-strip 0..7
    int xsc = rem & 15;                        // x-strip 0..15
    int yb  = ysr * TSY;
    int xb  = xsc * TSX;
    int cb  = min(max(xb - HALO, 0), W - LSTC);   // staged col origin

    int tid  = threadIdx.x;
    int wv   = tid >> 6;                       // 0..15
    int lane = tid & 63;
    int ryb  = wv * 4 + (lane >> 5);           // rows: ryb, ryb+2
    int x    = xb + (lane & 31);

    // ---- 1) dx/dy FIRST (oldest vmem: their waits leave staging in flight)
    float dxa[NPOS], dya[NPOS];
#pragma unroll
    for (int p = 0; p < NPOS; ++p) {
        int po = (yb + ryb + 2 * p) * W + x;
        dxa[p] = __builtin_nontemporal_load(dxp + bd * HW + po);
        dya[p] = __builtin_nontemporal_load(dyp + bd * HW + po);
    }

    // ---- 2) staging: 1 gload_lds16 per wave per plane (57 active lanes) --
    if (lane < CPW) {
        int chunk = wv * CPW + lane;           // < 912
        int r  = chunk / CHR;
        int c4 = (chunk - r * CHR) * 4;
        int sr = min(max(yb - HALO + r, 0), H - 1);   // y clamp == ref clamp
        int soff = sr * W + cb + c4;                  // always in-bounds
        const float* g0 = img + (size_t)bd * HW + soff;
        float* l0 = &tile[0][chunk * 4];
        gload_lds16(g0,          l0);
        gload_lds16(g0 + 4 * HW, l0 + TDW);
        gload_lds16(g0 + 8 * HW, l0 + 2 * TDW);
    }

    // ---- 3) coefficients (once per px, reused x3 planes) -----------------
    float wx[NPOS][4], cyw[NPOS][4];
    int   lbase[NPOS];
    unsigned relv[NPOS], lsv[NPOS];
    bool  intile[NPOS];
#pragma unroll
    for (int p = 0; p < NPOS; ++p) {
        int y = yb + ryb + 2 * p;
        float xm = (float)x + dxa[p];          // == ref up to ~3e-5 px rounding
        float ym = (float)y + dya[p];
        float x0f = floorf(xm), y0f = floorf(ym);
        float ftx = xm - x0f, fty = ym - y0f;
        int x0 = (int)x0f, y0 = (int)y0f;
        int s  = min(max(x0 - 1, 0), W - 4);

        float tx2 = ftx * ftx, tx3 = tx2 * ftx;
        float cx0 = (-tx3 + 2.0f * tx2 - ftx) * 0.5f;
        float cx1 = (3.0f * tx3 - 5.0f * tx2 + 2.0f) * 0.5f;
        float cx2 = (-3.0f * tx3 + 4.0f * tx2 + ftx) * 0.5f;
        float cx3 = 1.0f - (cx0 + cx1 + cx2);

        float ty2 = fty * fty, ty3 = ty2 * fty;
        cyw[p][0] = (-ty3 + 2.0f * ty2 - fty) * 0.5f;
        cyw[p][1] = (3.0f * ty3 - 5.0f * ty2 + 2.0f) * 0.5f;
        cyw[p][2] = (-3.0f * ty3 + 4.0f * ty2 + fty) * 0.5f;
        cyw[p][3] = 1.0f - (cyw[p][0] + cyw[p][1] + cyw[p][2]);

        if (__builtin_expect(x0 >= 1 && x0 <= W - 3, 1)) {
            wx[p][0] = cx0; wx[p][1] = cx1; wx[p][2] = cx2; wx[p][3] = cx3;
        } else {                               // fold image-edge taps into window
            float w0 = 0.f, w1 = 0.f, w2 = 0.f, w3 = 0.f;
            const float cxa[4] = {cx0, cx1, cx2, cx3};
#pragma unroll
            for (int o = 0; o < 4; ++o) {
                int xi = min(max(x0 - 1 + o, 0), W - 1);
                int e  = xi - s;               // 0..3 always
                float cc = cxa[o];
                w0 += (e == 0) ? cc : 0.f;
                w1 += (e == 1) ? cc : 0.f;
                w2 += (e == 2) ? cc : 0.f;
                w3 += (e == 3) ? cc : 0.f;
            }
            wx[p][0] = w0; wx[p][1] = w1; wx[p][2] = w2; wx[p][3] = w3;
        }

        relv[p]  = (unsigned)(y0 - (yb - HALO + 1));  // staged row of y0-1
        lsv[p]   = (unsigned)(s - cb);                // staged col of window
        intile[p] = (relv[p] <= (unsigned)(RS - 4)) & (lsv[p] <= (unsigned)(LSTC - 4));
        lbase[p] = (int)relv[p] * LSTC + (int)lsv[p];
    }

    __syncthreads();   // single barrier: all 3 plane tiles landed

    // ---- 4) stencil: 3 planes x 2 positions, pure LDS + FMA + NT store ---
#pragma unroll
    for (int c = 0; c < C; ++c) {
        int kp = bd + 4 * c;
        const float* __restrict__ tp = &tile[c][0];
#pragma unroll
        for (int p = 0; p < NPOS; ++p) {
            int po = (yb + ryb + 2 * p) * W + x;
            float acc;
            if (__builtin_expect(intile[p], 1)) {
                const float* rp = tp + lbase[p];
                float r0 = cyw[p][0] * (wx[p][0]*rp[0] + wx[p][1]*rp[1] + wx[p][2]*rp[2] + wx[p][3]*rp[3]);
                rp += LSTC;
                float r1 = cyw[p][1] * (wx[p][0]*rp[0] + wx[p][1]*rp[1] + wx[p][2]*rp[2] + wx[p][3]*rp[3]);
                rp += LSTC;
                float r2 = cyw[p][2] * (wx[p][0]*rp[0] + wx[p][1]*rp[1] + wx[p][2]*rp[2] + wx[p][3]*rp[3]);
                rp += LSTC;
                float r3 = cyw[p][3] * (wx[p][0]*rp[0] + wx[p][1]*rp[1] + wx[p][2]*rp[2] + wx[p][3]*rp[3]);
                acc = (r0 + r1) + (r2 + r3);
            } else {
                // rare Gaussian-tail escape: always-correct global path
                const float* __restrict__ plane = img + (size_t)kp * HW;
                int y0 = (int)relv[p] + (yb - HALO + 1);
                int s  = (int)lsv[p] + cb;
                acc = 0.f;
#pragma unroll
                for (int j = 0; j < 4; ++j) {
                    int yi = min(max(y0 - 1 + j, 0), H - 1);
                    f4 v = *(const f4u*)(plane + yi * W + s);
                    acc += cyw[p][j] * (wx[p][0]*v.x + wx[p][1]*v.y + wx[p][2]*v.z + wx[p][3]*v.w);
                }
            }
            __builtin_nontemporal_store(acc, out + (size_t)kp * HW + po);
        }
    }
}

extern "C" void kernel_launch(void* const* d_in, const int* in_sizes, int n_in,
                              void* d_out, int out_size, void* d_ws, size_t ws_size,
                              hipStream_t stream) {
    const float* img = (const float*)d_in[0];
    const float* dx  = (const float*)d_in[1];
    const float* dy  = (const float*)d_in[2];
    float* out = (float*)d_out;

    dim3 block(NT);
    dim3 grid(NB);   // 512 blocks -> 2 resident/CU, whole grid co-resident
    hipLaunchKernelGGL(warp_bicubic_tall, grid, block, 0, stream,
                       img, dx, dy, out);
}

// Round 17
// 16.178 us; speedup vs baseline: 1.1160x; 1.0228x over previous
//
#include <hip/hip_runtime.h>

// Warp_Object bicubic warp: B=4, C=3, H=512, W=512, float32.
// FINAL (= round-13 kernel, best measured: 16.05us). Session plateau:
// 8 structural variants band-limited at 16.0-16.9us; overlapped pipe floor
// ~8-9us unreachable via counted-vmcnt / 2-deep / 4-deep pipelines (all
// null). Structure: 32x32 tiles, halo 6, all 3 channel planes staged at
// once via global_load_lds w=16 (planes share displacement -> one coeff
// set reused x3), single barrier, NT stores, XCD-chunked swizzle,
// 2 dispatch generations. Gaussian-tail escapees -> global fallback.

constexpr int B = 4, C = 3, H = 512, W = 512;
constexpr int HW = H * W;              // 2^18
constexpr int TH2 = 32, TW = 32;       // output tile
constexpr int HALO = 6;
constexpr int RS = TH2 + 2 * HALO;     // 44 staged rows
constexpr int LSTC = 48;               // staged cols; %32=16 bank rotate
constexpr int CHR = LSTC / 4;          // 12 f4 chunks per staged row
constexpr int NCH = RS * CHR;          // 528 chunks per plane
constexpr int CPW = NCH / 16;          // 33 chunks per wave per plane
constexpr int TDW = RS * LSTC;         // 2112 dwords per plane
constexpr int NT = 1024;
constexpr int NB = B * (H / TH2) * (W / TW);   // 1024 blocks

typedef float f4 __attribute__((ext_vector_type(4)));
typedef f4 f4u __attribute__((aligned(4)));   // 4B-aligned float4 load

typedef const __attribute__((address_space(1))) void* gas_t;
typedef __attribute__((address_space(3))) void* las_t;

__device__ __forceinline__ void gload_lds16(const float* g, float* l) {
    __builtin_amdgcn_global_load_lds((gas_t)g, (las_t)l, 16, 0, 0);
}

__global__ __launch_bounds__(NT, 8)
void warp_bicubic_gen(const float* __restrict__ img,
                      const float* __restrict__ dxp,
                      const float* __restrict__ dyp,
                      float* __restrict__ out)
{
    __shared__ float tile[C][TDW];             // 25,344 B -> 2 blocks/CU resident

    int b   = blockIdx.x;
    int swz = (b & 7) * (NB / 8) + (b >> 3);   // XCD-chunked, bijective (1024=8*128)
    int bd  = swz >> 8;                        // displacement batch 0..3
    int ty  = (swz >> 4) & 15;
    int tx  = swz & 15;
    int yb  = ty * TH2;
    int xb  = tx * TW;
    int cb  = min(max(xb - HALO, 0), W - LSTC);   // staged col origin, in-bounds

    int tid  = threadIdx.x;
    int wv   = tid >> 6;                       // 0..15
    int lane = tid & 63;
    int ry   = wv * 2 + (lane >> 5);           // 0..31
    int cidx = lane & 31;
    int y    = yb + ry;
    int x    = xb + cidx;
    int pixoff = y * W + x;

    // ---- 1) dx/dy first (oldest vmem ops: coeff wait leaves staging in flight)
    float dxv = __builtin_nontemporal_load(dxp + bd * HW + pixoff);
    float dyv = __builtin_nontemporal_load(dyp + bd * HW + pixoff);

    // ---- 2) staging: 1 gload_lds16 per wave per plane, shared address math
    if (lane < CPW) {
        int chunk = wv * CPW + lane;           // < 528
        int r  = chunk / CHR;
        int c4 = (chunk - r * CHR) * 4;
        int sr = min(max(yb - HALO + r, 0), H - 1);   // y clamp == ref row clamp
        int soff = sr * W + cb + c4;                  // always in [0, HW-4]
        const float* g0 = img + (size_t)bd * HW + soff;
        float* l0 = &tile[0][chunk * 4];
        gload_lds16(g0,           l0);
        gload_lds16(g0 + 4 * HW,  l0 + TDW);
        gload_lds16(g0 + 8 * HW,  l0 + 2 * TDW);
    }

    // ---- 3) coefficients (one position, reused x3 planes) ----
    float xm = (float)x + dxv;                 // == ref up to ~3e-5 px rounding
    float ym = (float)y + dyv;
    float x0f = floorf(xm), y0f = floorf(ym);
    float ftx = xm - x0f, fty = ym - y0f;
    int x0 = (int)x0f, y0 = (int)y0f;
    int s  = min(max(x0 - 1, 0), W - 4);       // 4-wide window start (image cols)

    float tx2 = ftx * ftx, tx3 = tx2 * ftx;
    float cx0 = (-tx3 + 2.0f * tx2 - ftx) * 0.5f;
    float cx1 = (3.0f * tx3 - 5.0f * tx2 + 2.0f) * 0.5f;
    float cx2 = (-3.0f * tx3 + 4.0f * tx2 + ftx) * 0.5f;
    float cx3 = 1.0f - (cx0 + cx1 + cx2);

    float ty2 = fty * fty, ty3 = ty2 * fty;
    float cy0 = (-ty3 + 2.0f * ty2 - fty) * 0.5f;
    float cy1 = (3.0f * ty3 - 5.0f * ty2 + 2.0f) * 0.5f;
    float cy2 = (-3.0f * ty3 + 4.0f * ty2 + fty) * 0.5f;
    float cy3 = 1.0f - (cy0 + cy1 + cy2);

    float w0, w1, w2, w3;
    if (__builtin_expect(x0 >= 1 && x0 <= W - 3, 1)) {   // interior: weights = cx
        w0 = cx0; w1 = cx1; w2 = cx2; w3 = cx3;
    } else {                                   // fold image-edge taps into window
        w0 = w1 = w2 = w3 = 0.f;
        const float cxa[4] = {cx0, cx1, cx2, cx3};
#pragma unroll
        for (int o = 0; o < 4; ++o) {
            int xi = min(max(x0 - 1 + o, 0), W - 1);
            int e  = xi - s;                   // 0..3 always
            float cc = cxa[o];
            w0 += (e == 0) ? cc : 0.f;
            w1 += (e == 1) ? cc : 0.f;
            w2 += (e == 2) ? cc : 0.f;
            w3 += (e == 3) ? cc : 0.f;
        }
    }

    unsigned rel = (unsigned)(y0 - (yb - HALO + 1));     // staged row of y0-1
    unsigned lsv = (unsigned)(s - cb);                   // staged col of window
    bool intile = (rel <= (unsigned)(RS - 4)) & (lsv <= (unsigned)(LSTC - 4));
    int lbase = (int)rel * LSTC + (int)lsv;

    __syncthreads();   // single barrier: all 3 plane tiles landed

    // ---- 4) stencil: 3 planes, pure LDS + FMA + NT store ----
#pragma unroll
    for (int c = 0; c < C; ++c) {
        int kp = bd + 4 * c;
        const float* __restrict__ tp = &tile[c][0];
        float acc;
        if (__builtin_expect(intile, 1)) {
            const float* rp = tp + lbase;
            float r0 = cy0 * (w0 * rp[0] + w1 * rp[1] + w2 * rp[2] + w3 * rp[3]);
            rp += LSTC;
            float r1 = cy1 * (w0 * rp[0] + w1 * rp[1] + w2 * rp[2] + w3 * rp[3]);
            rp += LSTC;
            float r2 = cy2 * (w0 * rp[0] + w1 * rp[1] + w2 * rp[2] + w3 * rp[3]);
            rp += LSTC;
            float r3 = cy3 * (w0 * rp[0] + w1 * rp[1] + w2 * rp[2] + w3 * rp[3]);
            acc = (r0 + r1) + (r2 + r3);
        } else {
            // rare Gaussian-tail escape: always-correct global path
            const float* __restrict__ plane = img + (size_t)kp * HW;
            const float cya[4] = {cy0, cy1, cy2, cy3};
            acc = 0.f;
#pragma unroll
            for (int j = 0; j < 4; ++j) {
                int yi = min(max(y0 - 1 + j, 0), H - 1);
                f4 v = *(const f4u*)(plane + yi * W + s);
                acc += cya[j] * (w0 * v.x + w1 * v.y + w2 * v.z + w3 * v.w);
            }
        }
        __builtin_nontemporal_store(acc, out + (size_t)kp * HW + pixoff);
    }
}

extern "C" void kernel_launch(void* const* d_in, const int* in_sizes, int n_in,
                              void* d_out, int out_size, void* d_ws, size_t ws_size,
                              hipStream_t stream) {
    const float* img = (const float*)d_in[0];
    const float* dx  = (const float*)d_in[1];
    const float* dy  = (const float*)d_in[2];
    float* out = (float*)d_out;

    dim3 block(NT);
    dim3 grid(NB);   // 1024 blocks, 512 resident -> 2 dispatch generations
    hipLaunchKernelGGL(warp_bicubic_gen, grid, block, 0, stream,
                       img, dx, dy, out);
}